// Round 3
// baseline (1065.336 us; speedup 1.0000x reference)
//
#include <hip/hip_runtime.h>
#include <math.h>

#define D      512
#define NWAY   64
#define EPSF   1e-30f

// ============================ P1: partial segment sums ============================
// grid (nrb, 8): each block accumulates P1_ROWS rows x 64 dims into LDS, then
// flushes either to per-block partials (plain stores) or to a single global
// accumulator (atomicAdd), selected by `atomic_mode` (host branches on ws_size).
//
// psum row stride = 65 floats: ds_add_f32 bank = (65*l + 4*d4 + c) % 32
// = (l + 4*d4 + c) % 32 -> the wave's 64 lanes cover all 32 banks exactly
// twice (2-way aliasing is free, m136). Stride 68 was an 8-way conflict:
// bank = 4*(l+d4)+c hits only 8 banks. Scalar init/flush (rows unaligned
// for float4) -- 4096 scalars/block vs 65536 atomics/block, negligible.
#define P1_ROWS 1024
#define P1_DS   64
#define P1_STR  65

__global__ __launch_bounds__(256) void proto_partial(
    const float* __restrict__ sup, const int* __restrict__ lab,
    float* __restrict__ part, float* __restrict__ cpart,
    int n_sup, int atomic_mode)
{
    __shared__ float psum[NWAY][P1_STR];
    __shared__ float cnt[NWAY];
    const int t  = threadIdx.x;
    const int rb = blockIdx.x;
    const int dq = blockIdx.y;
    const int dbase = dq * P1_DS;

    for (int i = t; i < NWAY * P1_STR; i += 256) ((float*)psum)[i] = 0.f;
    if (t < NWAY) cnt[t] = 0.f;
    __syncthreads();

    const int d4 = t & 15;        // 16 float4 groups = 64 dims
    const int r  = t >> 4;        // 16 concurrent rows per 256 threads
    const int row0 = rb * P1_ROWS;

    #pragma unroll 4
    for (int it = 0; it < P1_ROWS / 16; ++it) {
        const int row = row0 + it * 16 + r;
        if (row < n_sup) {
            const int l   = lab[row];
            const float4 v = *(const float4*)&sup[(size_t)row * D + dbase + d4 * 4];
            atomicAdd(&psum[l][d4 * 4 + 0], v.x);
            atomicAdd(&psum[l][d4 * 4 + 1], v.y);
            atomicAdd(&psum[l][d4 * 4 + 2], v.z);
            atomicAdd(&psum[l][d4 * 4 + 3], v.w);
            if (dq == 0 && d4 == 0) atomicAdd(&cnt[l], 1.f);
        }
    }
    __syncthreads();

    if (!atomic_mode) {
        for (int i = t; i < NWAY * P1_DS; i += 256) {
            const int c = i >> 6, d = i & 63;    // consecutive lanes -> consecutive d
            part[((size_t)rb * NWAY + c) * D + dbase + d] = psum[c][d];
        }
        if (dq == 0 && t < NWAY) cpart[rb * NWAY + t] = cnt[t];
    } else {
        for (int i = t; i < NWAY * P1_DS; i += 256) {
            const int c = i >> 6, d = i & 63;
            atomicAdd(&part[(size_t)c * D + dbase + d], psum[c][d]);
        }
        if (dq == 0 && t < NWAY) atomicAdd(&cpart[t], cnt[t]);
    }
}

// Zero-init for the atomic path (ws is re-poisoned 0xAA before every launch).
__global__ void zero_ws(float* __restrict__ p, int n)
{
    const int i = blockIdx.x * 256 + threadIdx.x;
    if (i < n) p[i] = 0.f;
}

// ============================ P2: finalize prototypes ============================
// P'[c][k] = (sum/count) * scale / max(||prot||, eps)  -- pn and scale folded in.
// Works for any nrb >= 1 (atomic path passes nrb=1).
__global__ __launch_bounds__(256) void proto_finalize(
    const float* __restrict__ part, const float* __restrict__ cpart,
    const float* __restrict__ scale_p, float* __restrict__ Pg, int nrb)
{
    const int c  = blockIdx.x;
    const int t  = threadIdx.x;
    const int d4 = t & 127;       // 128 float4 groups = 512 dims
    const int rh = t >> 7;        // split partial-reduction over 2 halves

    float4 acc = make_float4(0.f, 0.f, 0.f, 0.f);
    for (int rb = rh; rb < nrb; rb += 2) {
        const float4 v = *(const float4*)&part[((size_t)rb * NWAY + c) * D + d4 * 4];
        acc.x += v.x; acc.y += v.y; acc.z += v.z; acc.w += v.w;
    }
    __shared__ float4 tmpv[128];
    if (rh == 1) tmpv[d4] = acc;
    __syncthreads();

    float cntv = 0.f;
    for (int rb = 0; rb < nrb; ++rb) cntv += cpart[rb * NWAY + c];

    float  ss   = 0.f;
    float4 prot = make_float4(0.f, 0.f, 0.f, 0.f);
    if (rh == 0) {
        const float4 o = tmpv[d4];
        acc.x += o.x; acc.y += o.y; acc.z += o.z; acc.w += o.w;
        const float ic = 1.f / cntv;
        prot = make_float4(acc.x * ic, acc.y * ic, acc.z * ic, acc.w * ic);
        ss = prot.x * prot.x + prot.y * prot.y + prot.z * prot.z + prot.w * prot.w;
    }
    #pragma unroll
    for (int off = 32; off > 0; off >>= 1) ss += __shfl_down(ss, off);
    __shared__ float red[4];
    if ((t & 63) == 0) red[t >> 6] = ss;
    __syncthreads();
    if (rh == 0) {
        const float pn = fmaxf(sqrtf(red[0] + red[1]), EPSF);
        const float f  = scale_p[0] / pn;
        *(float4*)&Pg[(size_t)c * D + d4 * 4] =
            make_float4(prot.x * f, prot.y * f, prot.z * f, prot.w * f);
    }
}

// ============================ G: logits GEMM ============================
// 128 queries x 64 classes per block, K=512 in double-buffered chunks of 32.
// Per-thread 8m x 4n fp32 register tile. LDS rows are 32 words (stride ≡ 0 mod 32
// banks) -> XOR-swizzle the k-offset with ((row>>3)&7)<<2 to spread bank quads.
// Query norms accumulated during staging (each element staged exactly once).
#define KC 32
#define MT 128
#define NCHUNK (D / KC)

__global__ __launch_bounds__(256, 2) void gemm_logits(
    const float* __restrict__ Qg, const float* __restrict__ Pg,
    float* __restrict__ out)
{
    __shared__ float Qs[2][MT][KC];
    __shared__ float Ps[2][NWAY][KC];
    __shared__ float qqs[MT];

    const int t  = threadIdx.x;
    const int m0 = blockIdx.x * MT;
    const int tn = t & 15;        // 16 n-groups * 4 classes
    const int tm = t >> 4;        // 16 m-groups * 8 rows
    const int kg = t & 7;         // staging: 8 k-groups (float4) = 32 k
    const int mb = t >> 3;        // staging: 32 row slots

    for (int i = t; i < MT; i += 256) qqs[i] = 0.f;

    float acc[8][4];
    #pragma unroll
    for (int i = 0; i < 8; ++i)
        #pragma unroll
        for (int j = 0; j < 4; ++j) acc[i][j] = 0.f;

    float4 qreg[4], preg[2];

    auto load_regs = [&](int ch) {
        const int kc = ch * KC;
        #pragma unroll
        for (int r2 = 0; r2 < 4; ++r2)
            qreg[r2] = *(const float4*)&Qg[(size_t)(m0 + mb + 32 * r2) * D + kc + kg * 4];
        #pragma unroll
        for (int h = 0; h < 2; ++h)
            preg[h] = *(const float4*)&Pg[(size_t)(mb + 32 * h) * D + kc + kg * 4];
    };
    auto write_lds = [&](int ch) {
        const int buf = ch & 1;
        #pragma unroll
        for (int r2 = 0; r2 < 4; ++r2) {
            const int m  = mb + 32 * r2;
            const int sw = ((m >> 3) & 7) << 2;
            *(float4*)&Qs[buf][m][(kg * 4) ^ sw] = qreg[r2];
            float s = qreg[r2].x * qreg[r2].x;
            s = fmaf(qreg[r2].y, qreg[r2].y, s);
            s = fmaf(qreg[r2].z, qreg[r2].z, s);
            s = fmaf(qreg[r2].w, qreg[r2].w, s);
            atomicAdd(&qqs[m], s);
        }
        #pragma unroll
        for (int h = 0; h < 2; ++h) {
            const int c  = mb + 32 * h;
            const int sw = ((c >> 2) & 7) << 2;
            *(float4*)&Ps[buf][c][(kg * 4) ^ sw] = preg[h];
        }
    };
    auto compute = [&](int buf) {
        const int swq = (tm & 7) << 2;   // == ((m>>3)&7)<<2 for m = tm*8+i
        const int swp = (tn & 7) << 2;   // == ((c>>2)&7)<<2 for c = tn*4+j
        #pragma unroll
        for (int kk = 0; kk < KC; kk += 4) {
            float4 a[8], b[4];
            const int kq = kk ^ swq;
            const int kp = kk ^ swp;
            #pragma unroll
            for (int i = 0; i < 8; ++i)
                a[i] = *(const float4*)&Qs[buf][tm * 8 + i][kq];
            #pragma unroll
            for (int j = 0; j < 4; ++j)
                b[j] = *(const float4*)&Ps[buf][tn * 4 + j][kp];
            #pragma unroll
            for (int i = 0; i < 8; ++i)
                #pragma unroll
                for (int j = 0; j < 4; ++j) {
                    float s = fmaf(a[i].x, b[j].x, acc[i][j]);
                    s = fmaf(a[i].y, b[j].y, s);
                    s = fmaf(a[i].z, b[j].z, s);
                    s = fmaf(a[i].w, b[j].w, s);
                    acc[i][j] = s;
                }
        }
    };

    load_regs(0);
    __syncthreads();          // qqs zero-init visible before first atomics
    write_lds(0);
    for (int ch = 0; ch < NCHUNK; ++ch) {
        if (ch + 1 < NCHUNK) load_regs(ch + 1);
        __syncthreads();      // chunk ch's LDS writes visible; prev compute done
        compute(ch & 1);
        if (ch + 1 < NCHUNK) write_lds(ch + 1);  // other buffer: no barrier needed
    }
    __syncthreads();

    #pragma unroll
    for (int i = 0; i < 8; ++i) {
        const int  m  = tm * 8 + i;
        const float qn = fmaxf(sqrtf(qqs[m]), EPSF);
        const float qi = 1.f / qn;
        float4 o = make_float4(acc[i][0] * qi, acc[i][1] * qi,
                               acc[i][2] * qi, acc[i][3] * qi);
        *(float4*)&out[(size_t)(m0 + m) * NWAY + tn * 4] = o;
    }
}

// ============================ launch ============================
extern "C" void kernel_launch(void* const* d_in, const int* in_sizes, int n_in,
                              void* d_out, int out_size, void* d_ws, size_t ws_size,
                              hipStream_t stream)
{
    const float* sup     = (const float*)d_in[0];
    const int*   slab    = (const int*)d_in[1];
    const float* qry     = (const float*)d_in[2];
    const float* scale_p = (const float*)d_in[4];

    const int n_sup = in_sizes[0] / D;
    const int n_qry = in_sizes[2] / D;
    const int nrb   = (n_sup + P1_ROWS - 1) / P1_ROWS;   // 64 for reference shape

    // Partials path needs: part[nrb][64][512] + cpart[nrb][64] + Pg[64][512]
    const size_t need_partials =
        ((size_t)nrb * NWAY * D + (size_t)nrb * NWAY + (size_t)NWAY * D) * sizeof(float);

    // ws_size is constant across calls -> this branch is deterministic (graph-safe).
    if (ws_size >= need_partials) {
        float* part  = (float*)d_ws;
        float* cpart = part + (size_t)nrb * NWAY * D;
        float* Pg    = cpart + (size_t)nrb * NWAY;

        proto_partial <<<dim3(nrb, D / P1_DS), 256, 0, stream>>>(sup, slab, part, cpart, n_sup, 0);
        proto_finalize<<<NWAY, 256, 0, stream>>>(part, cpart, scale_p, Pg, nrb);
        gemm_logits   <<<n_qry / MT, 256, 0, stream>>>(qry, Pg, (float*)d_out);
    } else {
        // Small-ws fallback: single global accumulator (262 KB total).
        float* psumg = (float*)d_ws;                 // [64][512]
        float* cnt   = psumg + (size_t)NWAY * D;     // [64]
        float* Pg    = cnt + NWAY;                   // [64][512]
        const int nz = NWAY * D + NWAY;              // floats to zero

        zero_ws       <<<(nz + 255) / 256, 256, 0, stream>>>(psumg, nz);
        proto_partial <<<dim3(nrb, D / P1_DS), 256, 0, stream>>>(sup, slab, psumg, cnt, n_sup, 1);
        proto_finalize<<<NWAY, 256, 0, stream>>>(psumg, cnt, scale_p, Pg, 1);
        gemm_logits   <<<n_qry / MT, 256, 0, stream>>>(qry, Pg, (float*)d_out);
    }
}

// Round 5
// 515.649 us; speedup vs baseline: 2.0660x; 2.0660x over previous
//
#include <hip/hip_runtime.h>
#include <math.h>

#define D      512
#define NWAY   64
#define EPSF   1e-30f

// ============================ P1: partial segment sums ============================
// grid (nrb, 8): block = 4 waves, 1024 rows x 64 dims. One ROW per wave-iter:
// lane = dim (64 lanes x 64 dims), so psum[l][lane] has bank = lane%32 ->
// exactly 2 lanes/bank (free, m136) and no same-address aliasing within the
// wave. ds atomics are fire-and-forget (no RMW register chain) and HW handles
// the rare cross-wave same-label collision. Counts need no LDS in the loop:
// cnt_reg += (lane == label) makes lane c hold the count of class c.
#define P1_ROWS 1024
#define P1_DS   64

__global__ __launch_bounds__(256) void proto_partial(
    const float* __restrict__ sup, const int* __restrict__ lab,
    float* __restrict__ part, float* __restrict__ cpart,
    int n_sup, int atomic_mode)
{
    __shared__ float psum[NWAY][P1_DS];   // 16 KB
    __shared__ float cntw[4][NWAY];
    const int t    = threadIdx.x;
    const int lane = t & 63;
    const int w    = t >> 6;              // wave 0..3
    const int rb   = blockIdx.x;
    const int dq   = blockIdx.y;
    const int dbase = dq * P1_DS;

    for (int i = t; i < NWAY * P1_DS; i += 256) ((float*)psum)[i] = 0.f;
    __syncthreads();

    float cnt_reg = 0.f;
    const int row0 = rb * P1_ROWS + w;    // 4 waves interleave consecutive rows

    #pragma unroll 8
    for (int it = 0; it < P1_ROWS / 4; ++it) {
        const int row = row0 + it * 4;
        if (row < n_sup) {
            const int   l = lab[row];
            const float v = sup[(size_t)row * D + dbase + lane];
            atomicAdd(&psum[l][lane], v);
            if (lane == l) cnt_reg += 1.f;
        }
    }
    cntw[w][lane] = cnt_reg;
    __syncthreads();

    if (!atomic_mode) {
        for (int i = t; i < NWAY * P1_DS; i += 256) {
            const int c = i >> 6, d = i & 63;   // consecutive lanes -> consecutive d
            part[((size_t)rb * NWAY + c) * D + dbase + d] = psum[c][d];
        }
        if (dq == 0 && t < NWAY)
            cpart[rb * NWAY + t] = cntw[0][t] + cntw[1][t] + cntw[2][t] + cntw[3][t];
    } else {
        for (int i = t; i < NWAY * P1_DS; i += 256) {
            const int c = i >> 6, d = i & 63;
            atomicAdd(&part[(size_t)c * D + dbase + d], psum[c][d]);
        }
        if (dq == 0 && t < NWAY)
            atomicAdd(&cpart[t], cntw[0][t] + cntw[1][t] + cntw[2][t] + cntw[3][t]);
    }
}

// Zero-init for the atomic path (ws is re-poisoned 0xAA before every launch).
__global__ void zero_ws(float* __restrict__ p, int n)
{
    const int i = blockIdx.x * 256 + threadIdx.x;
    if (i < n) p[i] = 0.f;
}

// ============================ P2: finalize prototypes ============================
// P'[c][k] = (sum/count) * scale / max(||prot||, eps)  -- pn and scale folded in.
// Works for any nrb >= 1 (atomic path passes nrb=1).
__global__ __launch_bounds__(256) void proto_finalize(
    const float* __restrict__ part, const float* __restrict__ cpart,
    const float* __restrict__ scale_p, float* __restrict__ Pg, int nrb)
{
    const int c  = blockIdx.x;
    const int t  = threadIdx.x;
    const int d4 = t & 127;       // 128 float4 groups = 512 dims
    const int rh = t >> 7;        // split partial-reduction over 2 halves

    float4 acc = make_float4(0.f, 0.f, 0.f, 0.f);
    for (int rb = rh; rb < nrb; rb += 2) {
        const float4 v = *(const float4*)&part[((size_t)rb * NWAY + c) * D + d4 * 4];
        acc.x += v.x; acc.y += v.y; acc.z += v.z; acc.w += v.w;
    }
    __shared__ float4 tmpv[128];
    if (rh == 1) tmpv[d4] = acc;
    __syncthreads();

    float cntv = 0.f;
    for (int rb = 0; rb < nrb; ++rb) cntv += cpart[rb * NWAY + c];

    float  ss   = 0.f;
    float4 prot = make_float4(0.f, 0.f, 0.f, 0.f);
    if (rh == 0) {
        const float4 o = tmpv[d4];
        acc.x += o.x; acc.y += o.y; acc.z += o.z; acc.w += o.w;
        const float ic = 1.f / cntv;
        prot = make_float4(acc.x * ic, acc.y * ic, acc.z * ic, acc.w * ic);
        ss = prot.x * prot.x + prot.y * prot.y + prot.z * prot.z + prot.w * prot.w;
    }
    #pragma unroll
    for (int off = 32; off > 0; off >>= 1) ss += __shfl_down(ss, off);
    __shared__ float red[4];
    if ((t & 63) == 0) red[t >> 6] = ss;
    __syncthreads();
    if (rh == 0) {
        const float pn = fmaxf(sqrtf(red[0] + red[1]), EPSF);
        const float f  = scale_p[0] / pn;
        *(float4*)&Pg[(size_t)c * D + d4 * 4] =
            make_float4(prot.x * f, prot.y * f, prot.z * f, prot.w * f);
    }
}

// ============================ G: logits GEMM ============================
// 128 queries x 64 classes per block, K=512 in double-buffered chunks of 32.
// Per-thread 8m x 4n fp32 register tile.
//
// Round-3 spill fix: rocprof showed WRITE_SIZE 1.64 GB (100x the 16.8 MB
// output) + VALUBusy 6% at VGPR_Count=128 -> the a[8]/b[4] float4 arrays were
// spilling to scratch every kk-step. Compute loop restructured: load b[4]
// once per kk-step, stream a one float4 at a time (live set ~90 regs).
// qqs LDS atomics replaced by register accumulation + shfl_xor(width=8)
// reduce (each thread stages the same rows every chunk).
#define KC 32
#define MT 128
#define NCHUNK (D / KC)

__global__ __launch_bounds__(256) void gemm_logits(
    const float* __restrict__ Qg, const float* __restrict__ Pg,
    float* __restrict__ out)
{
    __shared__ float Qs[2][MT][KC];
    __shared__ float Ps[2][NWAY][KC];
    __shared__ float qqs[MT];

    const int t  = threadIdx.x;
    const int m0 = blockIdx.x * MT;
    const int tn = t & 15;        // 16 n-groups * 4 classes
    const int tm = t >> 4;        // 16 m-groups * 8 rows
    const int kg = t & 7;         // staging: 8 k-groups (float4) = 32 k
    const int mb = t >> 3;        // staging: 32 row slots

    float acc[8][4];
    #pragma unroll
    for (int i = 0; i < 8; ++i)
        #pragma unroll
        for (int j = 0; j < 4; ++j) acc[i][j] = 0.f;

    float qq_reg[4] = {0.f, 0.f, 0.f, 0.f};
    float4 qreg[4], preg[2];

    auto load_regs = [&](int ch) {
        const int kc = ch * KC;
        #pragma unroll
        for (int r2 = 0; r2 < 4; ++r2)
            qreg[r2] = *(const float4*)&Qg[(size_t)(m0 + mb + 32 * r2) * D + kc + kg * 4];
        #pragma unroll
        for (int h = 0; h < 2; ++h)
            preg[h] = *(const float4*)&Pg[(size_t)(mb + 32 * h) * D + kc + kg * 4];
    };
    auto write_lds = [&](int ch) {
        const int buf = ch & 1;
        #pragma unroll
        for (int r2 = 0; r2 < 4; ++r2) {
            const int m  = mb + 32 * r2;
            const int sw = ((m >> 3) & 7) << 2;
            *(float4*)&Qs[buf][m][(kg * 4) ^ sw] = qreg[r2];
            float s = qreg[r2].x * qreg[r2].x;
            s = fmaf(qreg[r2].y, qreg[r2].y, s);
            s = fmaf(qreg[r2].z, qreg[r2].z, s);
            s = fmaf(qreg[r2].w, qreg[r2].w, s);
            qq_reg[r2] += s;              // register, not LDS atomic
        }
        #pragma unroll
        for (int h = 0; h < 2; ++h) {
            const int c  = mb + 32 * h;
            const int sw = ((c >> 2) & 7) << 2;
            *(float4*)&Ps[buf][c][(kg * 4) ^ sw] = preg[h];
        }
    };
    auto compute = [&](int buf) {
        const int swq = (tm & 7) << 2;   // == ((m>>3)&7)<<2 for m = tm*8+i
        const int swp = (tn & 7) << 2;   // == ((c>>2)&7)<<2 for c = tn*4+j
        #pragma unroll
        for (int kk = 0; kk < KC; kk += 4) {
            const int kq = kk ^ swq;
            const int kp = kk ^ swp;
            float4 b[4];
            #pragma unroll
            for (int j = 0; j < 4; ++j)
                b[j] = *(const float4*)&Ps[buf][tn * 4 + j][kp];
            #pragma unroll
            for (int i = 0; i < 8; ++i) {
                const float4 a = *(const float4*)&Qs[buf][tm * 8 + i][kq];
                #pragma unroll
                for (int j = 0; j < 4; ++j) {
                    float s = fmaf(a.x, b[j].x, acc[i][j]);
                    s = fmaf(a.y, b[j].y, s);
                    s = fmaf(a.z, b[j].z, s);
                    s = fmaf(a.w, b[j].w, s);
                    acc[i][j] = s;
                }
            }
        }
    };

    load_regs(0);
    write_lds(0);
    for (int ch = 0; ch < NCHUNK; ++ch) {
        if (ch + 1 < NCHUNK) load_regs(ch + 1);
        __syncthreads();      // chunk ch's LDS writes visible; prev compute done
        compute(ch & 1);
        if (ch + 1 < NCHUNK) write_lds(ch + 1);  // other buffer: no barrier needed
    }

    // q-norm: reduce qq over the 8 staging lanes (kg) that shared each row.
    #pragma unroll
    for (int r2 = 0; r2 < 4; ++r2) {
        float s = qq_reg[r2];
        s += __shfl_xor(s, 1, 8);
        s += __shfl_xor(s, 2, 8);
        s += __shfl_xor(s, 4, 8);
        if (kg == 0) qqs[mb + 32 * r2] = s;   // unique writer per row
    }
    __syncthreads();

    #pragma unroll
    for (int i = 0; i < 8; ++i) {
        const int  m  = tm * 8 + i;
        const float qn = fmaxf(sqrtf(qqs[m]), EPSF);
        const float qi = 1.f / qn;
        float4 o = make_float4(acc[i][0] * qi, acc[i][1] * qi,
                               acc[i][2] * qi, acc[i][3] * qi);
        *(float4*)&out[(size_t)(m0 + m) * NWAY + tn * 4] = o;
    }
}

// ============================ launch ============================
extern "C" void kernel_launch(void* const* d_in, const int* in_sizes, int n_in,
                              void* d_out, int out_size, void* d_ws, size_t ws_size,
                              hipStream_t stream)
{
    const float* sup     = (const float*)d_in[0];
    const int*   slab    = (const int*)d_in[1];
    const float* qry     = (const float*)d_in[2];
    const float* scale_p = (const float*)d_in[4];

    const int n_sup = in_sizes[0] / D;
    const int n_qry = in_sizes[2] / D;
    const int nrb   = (n_sup + P1_ROWS - 1) / P1_ROWS;   // 64 for reference shape

    // Partials path needs: part[nrb][64][512] + cpart[nrb][64] + Pg[64][512]
    const size_t need_partials =
        ((size_t)nrb * NWAY * D + (size_t)nrb * NWAY + (size_t)NWAY * D) * sizeof(float);

    // ws_size is constant across calls -> this branch is deterministic (graph-safe).
    if (ws_size >= need_partials) {
        float* part  = (float*)d_ws;
        float* cpart = part + (size_t)nrb * NWAY * D;
        float* Pg    = cpart + (size_t)nrb * NWAY;

        proto_partial <<<dim3(nrb, D / P1_DS), 256, 0, stream>>>(sup, slab, part, cpart, n_sup, 0);
        proto_finalize<<<NWAY, 256, 0, stream>>>(part, cpart, scale_p, Pg, nrb);
        gemm_logits   <<<n_qry / MT, 256, 0, stream>>>(qry, Pg, (float*)d_out);
    } else {
        // Small-ws fallback: single global accumulator (262 KB total).
        float* psumg = (float*)d_ws;                 // [64][512]
        float* cnt   = psumg + (size_t)NWAY * D;     // [64]
        float* Pg    = cnt + NWAY;                   // [64][512]
        const int nz = NWAY * D + NWAY;              // floats to zero

        zero_ws       <<<(nz + 255) / 256, 256, 0, stream>>>(psumg, nz);
        proto_partial <<<dim3(nrb, D / P1_DS), 256, 0, stream>>>(sup, slab, psumg, cnt, n_sup, 1);
        proto_finalize<<<NWAY, 256, 0, stream>>>(psumg, cnt, scale_p, Pg, 1);
        gemm_logits   <<<n_qry / MT, 256, 0, stream>>>(qry, Pg, (float*)d_out);
    }
}

// Round 6
// 511.799 us; speedup vs baseline: 2.0816x; 1.0075x over previous
//
#include <hip/hip_runtime.h>
#include <math.h>

#define D      512
#define NWAY   64
#define EPSF   1e-30f

// ============================ P1: partial segment sums ============================
// grid (nrb, 8): block = 4 waves, 1024 rows x 64 dims, lane = dim.
// psum[l][lane]: bank = lane%32 -> 2 lanes/bank (free, m136; measured 0 conflicts
// in round 5). Counts in registers: lane c counts class c.
//
// Round-5 latency fix: P1 measured 176us with VALUBusy 4.6%, HBM 5.4%, 0 bank
// conflicts -> ~1650 cyc/iteration = two serialized memory latencies. The
// per-iteration exec-mask guard + compiler scheduling kept only ~1 load in
// flight. Now: wave-uniform full-block branch + explicit 8-deep register batch
// (16 outstanding loads issued before the first atomic consumes one).
#define P1_ROWS 1024
#define P1_DS   64
#define P1_BATCH 8

__global__ __launch_bounds__(256) void proto_partial(
    const float* __restrict__ sup, const int* __restrict__ lab,
    float* __restrict__ part, float* __restrict__ cpart,
    int n_sup, int atomic_mode)
{
    __shared__ float psum[NWAY][P1_DS];   // 16 KB
    __shared__ float cntw[4][NWAY];
    const int t    = threadIdx.x;
    const int lane = t & 63;
    const int w    = t >> 6;              // wave 0..3
    const int rb   = blockIdx.x;
    const int dq   = blockIdx.y;
    const int dbase = dq * P1_DS;

    for (int i = t; i < NWAY * P1_DS; i += 256) ((float*)psum)[i] = 0.f;
    __syncthreads();

    float cnt_reg = 0.f;
    const int row0 = rb * P1_ROWS + w;    // 4 waves interleave consecutive rows
    const bool full = ((rb + 1) * P1_ROWS <= n_sup);   // wave-uniform

    if (full) {
        // 256 rows/wave = 32 batches of 8. All loads of a batch are issued
        // back-to-back into registers; atomics consume them afterwards, so
        // the compiler's counted vmcnt keeps ~16 loads in flight.
        for (int it = 0; it < (P1_ROWS / 4) / P1_BATCH; ++it) {
            int   lb[P1_BATCH];
            float vb[P1_BATCH];
            #pragma unroll
            for (int j = 0; j < P1_BATCH; ++j) {
                const int row = row0 + (it * P1_BATCH + j) * 4;
                lb[j] = lab[row];
                vb[j] = sup[(size_t)row * D + dbase + lane];
            }
            #pragma unroll
            for (int j = 0; j < P1_BATCH; ++j) {
                atomicAdd(&psum[lb[j]][lane], vb[j]);
                cnt_reg += (lane == lb[j]) ? 1.f : 0.f;
            }
        }
    } else {
        for (int it = 0; it < P1_ROWS / 4; ++it) {
            const int row = row0 + it * 4;
            if (row < n_sup) {
                const int   l = lab[row];
                const float v = sup[(size_t)row * D + dbase + lane];
                atomicAdd(&psum[l][lane], v);
                if (lane == l) cnt_reg += 1.f;
            }
        }
    }
    cntw[w][lane] = cnt_reg;
    __syncthreads();

    if (!atomic_mode) {
        for (int i = t; i < NWAY * P1_DS; i += 256) {
            const int c = i >> 6, d = i & 63;   // consecutive lanes -> consecutive d
            part[((size_t)rb * NWAY + c) * D + dbase + d] = psum[c][d];
        }
        if (dq == 0 && t < NWAY)
            cpart[rb * NWAY + t] = cntw[0][t] + cntw[1][t] + cntw[2][t] + cntw[3][t];
    } else {
        for (int i = t; i < NWAY * P1_DS; i += 256) {
            const int c = i >> 6, d = i & 63;
            atomicAdd(&part[(size_t)c * D + dbase + d], psum[c][d]);
        }
        if (dq == 0 && t < NWAY)
            atomicAdd(&cpart[t], cntw[0][t] + cntw[1][t] + cntw[2][t] + cntw[3][t]);
    }
}

// Zero-init for the atomic path (ws is re-poisoned 0xAA before every launch).
__global__ void zero_ws(float* __restrict__ p, int n)
{
    const int i = blockIdx.x * 256 + threadIdx.x;
    if (i < n) p[i] = 0.f;
}

// ============================ P2: finalize prototypes ============================
// P'[c][k] = (sum/count) * scale / max(||prot||, eps)  -- pn and scale folded in.
// Works for any nrb >= 1 (atomic path passes nrb=1).
__global__ __launch_bounds__(256) void proto_finalize(
    const float* __restrict__ part, const float* __restrict__ cpart,
    const float* __restrict__ scale_p, float* __restrict__ Pg, int nrb)
{
    const int c  = blockIdx.x;
    const int t  = threadIdx.x;
    const int d4 = t & 127;       // 128 float4 groups = 512 dims
    const int rh = t >> 7;        // split partial-reduction over 2 halves

    float4 acc = make_float4(0.f, 0.f, 0.f, 0.f);
    for (int rb = rh; rb < nrb; rb += 2) {
        const float4 v = *(const float4*)&part[((size_t)rb * NWAY + c) * D + d4 * 4];
        acc.x += v.x; acc.y += v.y; acc.z += v.z; acc.w += v.w;
    }
    __shared__ float4 tmpv[128];
    if (rh == 1) tmpv[d4] = acc;
    __syncthreads();

    float cntv = 0.f;
    for (int rb = 0; rb < nrb; ++rb) cntv += cpart[rb * NWAY + c];

    float  ss   = 0.f;
    float4 prot = make_float4(0.f, 0.f, 0.f, 0.f);
    if (rh == 0) {
        const float4 o = tmpv[d4];
        acc.x += o.x; acc.y += o.y; acc.z += o.z; acc.w += o.w;
        const float ic = 1.f / cntv;
        prot = make_float4(acc.x * ic, acc.y * ic, acc.z * ic, acc.w * ic);
        ss = prot.x * prot.x + prot.y * prot.y + prot.z * prot.z + prot.w * prot.w;
    }
    #pragma unroll
    for (int off = 32; off > 0; off >>= 1) ss += __shfl_down(ss, off);
    __shared__ float red[4];
    if ((t & 63) == 0) red[t >> 6] = ss;
    __syncthreads();
    if (rh == 0) {
        const float pn = fmaxf(sqrtf(red[0] + red[1]), EPSF);
        const float f  = scale_p[0] / pn;
        *(float4*)&Pg[(size_t)c * D + d4 * 4] =
            make_float4(prot.x * f, prot.y * f, prot.z * f, prot.w * f);
    }
}

// ============================ G: logits GEMM ============================
// 128 queries x 64 classes per block, K=512 in double-buffered chunks of 32.
// Per-thread 8m x 4n fp32 register tile. Spill-free since round 5 (b[4] loaded
// once per kk-step, a streamed; qq in registers + shfl reduce).
#define KC 32
#define MT 128
#define NCHUNK (D / KC)

__global__ __launch_bounds__(256) void gemm_logits(
    const float* __restrict__ Qg, const float* __restrict__ Pg,
    float* __restrict__ out)
{
    __shared__ float Qs[2][MT][KC];
    __shared__ float Ps[2][NWAY][KC];
    __shared__ float qqs[MT];

    const int t  = threadIdx.x;
    const int m0 = blockIdx.x * MT;
    const int tn = t & 15;        // 16 n-groups * 4 classes
    const int tm = t >> 4;        // 16 m-groups * 8 rows
    const int kg = t & 7;         // staging: 8 k-groups (float4) = 32 k
    const int mb = t >> 3;        // staging: 32 row slots

    float acc[8][4];
    #pragma unroll
    for (int i = 0; i < 8; ++i)
        #pragma unroll
        for (int j = 0; j < 4; ++j) acc[i][j] = 0.f;

    float qq_reg[4] = {0.f, 0.f, 0.f, 0.f};
    float4 qreg[4], preg[2];

    auto load_regs = [&](int ch) {
        const int kc = ch * KC;
        #pragma unroll
        for (int r2 = 0; r2 < 4; ++r2)
            qreg[r2] = *(const float4*)&Qg[(size_t)(m0 + mb + 32 * r2) * D + kc + kg * 4];
        #pragma unroll
        for (int h = 0; h < 2; ++h)
            preg[h] = *(const float4*)&Pg[(size_t)(mb + 32 * h) * D + kc + kg * 4];
    };
    auto write_lds = [&](int ch) {
        const int buf = ch & 1;
        #pragma unroll
        for (int r2 = 0; r2 < 4; ++r2) {
            const int m  = mb + 32 * r2;
            const int sw = ((m >> 3) & 7) << 2;
            *(float4*)&Qs[buf][m][(kg * 4) ^ sw] = qreg[r2];
            float s = qreg[r2].x * qreg[r2].x;
            s = fmaf(qreg[r2].y, qreg[r2].y, s);
            s = fmaf(qreg[r2].z, qreg[r2].z, s);
            s = fmaf(qreg[r2].w, qreg[r2].w, s);
            qq_reg[r2] += s;              // register, not LDS atomic
        }
        #pragma unroll
        for (int h = 0; h < 2; ++h) {
            const int c  = mb + 32 * h;
            const int sw = ((c >> 2) & 7) << 2;
            *(float4*)&Ps[buf][c][(kg * 4) ^ sw] = preg[h];
        }
    };
    auto compute = [&](int buf) {
        const int swq = (tm & 7) << 2;   // == ((m>>3)&7)<<2 for m = tm*8+i
        const int swp = (tn & 7) << 2;   // == ((c>>2)&7)<<2 for c = tn*4+j
        #pragma unroll
        for (int kk = 0; kk < KC; kk += 4) {
            const int kq = kk ^ swq;
            const int kp = kk ^ swp;
            float4 b[4];
            #pragma unroll
            for (int j = 0; j < 4; ++j)
                b[j] = *(const float4*)&Ps[buf][tn * 4 + j][kp];
            #pragma unroll
            for (int i = 0; i < 8; ++i) {
                const float4 a = *(const float4*)&Qs[buf][tm * 8 + i][kq];
                #pragma unroll
                for (int j = 0; j < 4; ++j) {
                    float s = fmaf(a.x, b[j].x, acc[i][j]);
                    s = fmaf(a.y, b[j].y, s);
                    s = fmaf(a.z, b[j].z, s);
                    s = fmaf(a.w, b[j].w, s);
                    acc[i][j] = s;
                }
            }
        }
    };

    load_regs(0);
    write_lds(0);
    for (int ch = 0; ch < NCHUNK; ++ch) {
        if (ch + 1 < NCHUNK) load_regs(ch + 1);
        __syncthreads();      // chunk ch's LDS writes visible; prev compute done
        compute(ch & 1);
        if (ch + 1 < NCHUNK) write_lds(ch + 1);  // other buffer: no barrier needed
    }

    // q-norm: reduce qq over the 8 staging lanes (kg) that shared each row.
    #pragma unroll
    for (int r2 = 0; r2 < 4; ++r2) {
        float s = qq_reg[r2];
        s += __shfl_xor(s, 1, 8);
        s += __shfl_xor(s, 2, 8);
        s += __shfl_xor(s, 4, 8);
        if (kg == 0) qqs[mb + 32 * r2] = s;   // unique writer per row
    }
    __syncthreads();

    #pragma unroll
    for (int i = 0; i < 8; ++i) {
        const int  m  = tm * 8 + i;
        const float qn = fmaxf(sqrtf(qqs[m]), EPSF);
        const float qi = 1.f / qn;
        float4 o = make_float4(acc[i][0] * qi, acc[i][1] * qi,
                               acc[i][2] * qi, acc[i][3] * qi);
        *(float4*)&out[(size_t)(m0 + m) * NWAY + tn * 4] = o;
    }
}

// ============================ launch ============================
extern "C" void kernel_launch(void* const* d_in, const int* in_sizes, int n_in,
                              void* d_out, int out_size, void* d_ws, size_t ws_size,
                              hipStream_t stream)
{
    const float* sup     = (const float*)d_in[0];
    const int*   slab    = (const int*)d_in[1];
    const float* qry     = (const float*)d_in[2];
    const float* scale_p = (const float*)d_in[4];

    const int n_sup = in_sizes[0] / D;
    const int n_qry = in_sizes[2] / D;
    const int nrb   = (n_sup + P1_ROWS - 1) / P1_ROWS;   // 64 for reference shape

    // Partials path needs: part[nrb][64][512] + cpart[nrb][64] + Pg[64][512]
    const size_t need_partials =
        ((size_t)nrb * NWAY * D + (size_t)nrb * NWAY + (size_t)NWAY * D) * sizeof(float);

    // ws_size is constant across calls -> this branch is deterministic (graph-safe).
    if (ws_size >= need_partials) {
        float* part  = (float*)d_ws;
        float* cpart = part + (size_t)nrb * NWAY * D;
        float* Pg    = cpart + (size_t)nrb * NWAY;

        proto_partial <<<dim3(nrb, D / P1_DS), 256, 0, stream>>>(sup, slab, part, cpart, n_sup, 0);
        proto_finalize<<<NWAY, 256, 0, stream>>>(part, cpart, scale_p, Pg, nrb);
        gemm_logits   <<<n_qry / MT, 256, 0, stream>>>(qry, Pg, (float*)d_out);
    } else {
        // Small-ws fallback: single global accumulator (262 KB total).
        float* psumg = (float*)d_ws;                 // [64][512]
        float* cnt   = psumg + (size_t)NWAY * D;     // [64]
        float* Pg    = cnt + NWAY;                   // [64][512]
        const int nz = NWAY * D + NWAY;              // floats to zero

        zero_ws       <<<(nz + 255) / 256, 256, 0, stream>>>(psumg, nz);
        proto_partial <<<dim3(nrb, D / P1_DS), 256, 0, stream>>>(sup, slab, psumg, cnt, n_sup, 1);
        proto_finalize<<<NWAY, 256, 0, stream>>>(psumg, cnt, scale_p, Pg, 1);
        gemm_logits   <<<n_qry / MT, 256, 0, stream>>>(qry, Pg, (float*)d_out);
    }
}